// Round 7
// baseline (477.976 us; speedup 1.0000x reference)
//
#include <hip/hip_runtime.h>
#include <hip/hip_bf16.h>

// R16: uniform-block edges_mfma. Diagnosis: OccupancyPercent ~20% at a
// nominal 16 waves/CU = intra-kernel imbalance tail (segregated s2s/a2s
// blocks; s2s ~2.3x a2s per-tile cost; ragged final round runs CUs half
// empty; makespan ~32 units vs ideal 21.4). Fix: EVERY block does its
// grid-stride share of s2s, barrier + WT reload (20KB, L2), then its share
// of a2s. edge_path bodies untouched (same 2 instantiations, sequential
// instead of branched). Grid 1024 = one full round of uniform blocks.
// Falsifier: VGPR > 128 (3 waves/SIMD) or edges >= 149.

typedef __attribute__((ext_vector_type(8))) short short8;
typedef __attribute__((ext_vector_type(4))) float f32x4;

#define MFMA(a, b, c) __builtin_amdgcn_mfma_f32_16x16x32_bf16(a, b, c, 0, 0, 0)

union FU { short8 v; unsigned int d[4]; unsigned short us[8]; };

__device__ __forceinline__ unsigned short f2bf(float f) {
    unsigned u = __float_as_uint(f);
    u += 0x7fffu + ((u >> 16) & 1u);   // RNE (data NaN-free)
    return (unsigned short)(u >> 16);
}
__device__ __forceinline__ unsigned int pk2(float a, float b) {
    float2 t; t.x = a; t.y = b;
    union { __hip_bfloat162 h; unsigned int u; } c;
    c.h = __float22bfloat162_rn(t);     // v_cvt_pk_bf16_f32
    return c.u;
}
__device__ __forceinline__ float tanh_fast(float xv) {
    float t = __builtin_amdgcn_exp2f(xv * 2.8853900817779268f); // 2*log2(e)
    return 1.0f - 2.0f * __builtin_amdgcn_rcpf(t + 1.0f);
}

// Build weight fragment tables in GLOBAL memory (once).
// frag(c,nt): lane holds W[k = c*32 + (lane>>4)*8 + j][n = nt*16 + (lane&15)].
template <typename KM>
__device__ void build_gfrags(const float* __restrict__ w, unsigned short* dst,
                             int nchunks, int gtid, int gstr, KM km) {
    int total = nchunks * 4 * 64;
    for (int f = gtid; f < total; f += gstr) {
        int lv = f & 63, nt = (f >> 6) & 3, c = f >> 8;
        int n = nt * 16 + (lv & 15);
        int kb = c * 32 + ((lv >> 4) << 3);
        unsigned short* o = dst + f * 8;
        #pragma unroll
        for (int j = 0; j < 8; ++j) {
            int sk = km(kb + j);
            o[j] = (sk >= 0) ? f2bf(w[sk * 64 + n]) : (unsigned short)0;
        }
    }
}

#define PERM_KM [](int k) -> int { return (k >> 2) + 16 * (k & 3); }

// C-layout (lane q,m16 holds row=q*4+r, feat=nt*16+m16) -> Zb[row][kpos],
// kpos = 4*m16 + nt; row stride 72 elems.
#define ZTRANS(Zw, accv)                                                       \
    _Pragma("unroll")                                                          \
    for (int r = 0; r < 4; ++r) {                                              \
        uint2 pv;                                                              \
        pv.x = pk2(tanh_fast(accv[0][r]), tanh_fast(accv[1][r]));              \
        pv.y = pk2(tanh_fast(accv[2][r]), tanh_fast(accv[3][r]));              \
        *(uint2*)((Zw) + ((q << 2) + r) * 72 + (m16 << 2)) = pv;               \
    }

// ---------------------------------------------------------------------------
// prep1: bf16 row tables (vectorized) + per-dst counts & ranks + wtab build
// ---------------------------------------------------------------------------
__global__ __launch_bounds__(256) void prep1(
    const float* __restrict__ ps, const float* __restrict__ pa,
    const float* __restrict__ h, const float* __restrict__ x,
    const float* __restrict__ u,
    const int* __restrict__ s2s_dst, const int* __restrict__ a2s_dst,
    unsigned short* __restrict__ s_row, unsigned short* __restrict__ a_row,
    int* __restrict__ cnt_s, int* __restrict__ rank_s,
    int* __restrict__ cnt_a, int* __restrict__ rank_a,
    const float* __restrict__ s_w1, const float* __restrict__ s_w2, const float* __restrict__ s_w3,
    const float* __restrict__ a_w1, const float* __restrict__ a_w2, const float* __restrict__ a_w3,
    const float* __restrict__ u_w1, const float* __restrict__ u_w2, const float* __restrict__ u_w3,
    unsigned short* __restrict__ ts, unsigned short* __restrict__ ta,
    unsigned short* __restrict__ tu,
    int NS, int NA, int ES, int EA, int MAINB)
{
    int bid = blockIdx.x;
    if (bid >= MAINB) {
        int gtid = (bid - MAINB) * 256 + threadIdx.x;
        int gstr = (gridDim.x - MAINB) * 256;
        build_gfrags(s_w1, ts, 3, gtid, gstr, [](int k) -> int {
            if (k < 2)   return k;          // ps_src
            if (k < 74)  return k + 3;      // x, h
            if (k < 80)  return -2;
            if (k < 82)  return k - 78;     // ps_dst
            if (k == 82) return 4;          // dis
            return -2; });
        build_gfrags(s_w2, ts + 3 * 2048, 2, gtid, gstr, PERM_KM);
        build_gfrags(s_w3, ts + 5 * 2048, 2, gtid, gstr, PERM_KM);
        build_gfrags(a_w1, ta, 1, gtid, gstr, [](int k) -> int {
            if (k < 2)   return k;          // pa
            if (k < 10)  return k + 3;      // u
            if (k < 16)  return -2;
            if (k < 18)  return k - 14;     // ps_dst
            if (k == 18) return 4;          // dis
            return -2; });
        build_gfrags(a_w2, ta + 1 * 2048, 2, gtid, gstr, PERM_KM);
        build_gfrags(a_w3, ta + 3 * 2048, 2, gtid, gstr, PERM_KM);
        // upd W1 with K-order [h(64) | su(64) | sxm(64) | ps(2), x(8)]
        build_gfrags(u_w1, tu, 7, gtid, gstr, [](int k) -> int {
            if (k < 192) return k + 2;      // h, su, sxm (orig 2..193)
            if (k < 194) return k - 192;    // ps (orig 0,1)
            if (k < 202) return k;          // x (orig 194..201)
            return -2; });
        build_gfrags(u_w2, tu + 7 * 2048, 2, gtid, gstr, PERM_KM);
        build_gfrags(u_w3, tu + 9 * 2048, 2, gtid, gstr, PERM_KM);
        return;
    }

    // padded index spaces: s_row NS*32 (20 active of 32), a_row NA*4, ranks
    int R0 = NS * 32, R1 = R0 + NA * 4, R2 = R1 + ES, R3 = R2 + EA;
    for (int i = bid * 256 + threadIdx.x; i < R3; i += MAINB * 256) {
        if (i < R0) {
            int n = i >> 5, kq = i & 31;
            if (kq < 20) {
                int k0 = kq << 2;
                float f[4];
                #pragma unroll
                for (int j = 0; j < 4; ++j) {
                    int k = k0 + j;
                    f[j] = (k < 2) ? ps[n * 2 + k] : (k < 10) ? x[n * 8 + k - 2]
                         : (k < 74) ? h[n * 64 + k - 10] : 0.f;
                }
                uint2 o; o.x = pk2(f[0], f[1]); o.y = pk2(f[2], f[3]);
                *(uint2*)&s_row[(size_t)n * 80 + k0] = o;
            }
        } else if (i < R1) {
            int j2 = i - R0; int a = j2 >> 2, kq = j2 & 3;
            int k0 = kq << 2;
            float f[4];
            #pragma unroll
            for (int j = 0; j < 4; ++j) {
                int k = k0 + j;
                f[j] = (k < 2) ? pa[a * 2 + k] : (k < 10) ? u[a * 8 + k - 2] : 0.f;
            }
            uint2 o; o.x = pk2(f[0], f[1]); o.y = pk2(f[2], f[3]);
            *(uint2*)&a_row[(size_t)a * 16 + k0] = o;
        } else if (i < R2) {
            int e = i - R1;
            rank_s[e] = atomicAdd(&cnt_s[s2s_dst[e]], 1);
        } else {
            int e = i - R2;
            rank_a[e] = atomicAdd(&cnt_a[a2s_dst[e]], 1);
        }
    }
}

// ---------------------------------------------------------------------------
// 3-phase multi-block exclusive scan over concatenated [cnt_s | cnt_a].
// ---------------------------------------------------------------------------
#define SCAN_CHUNK 1024

__global__ __launch_bounds__(256) void scan_a(const int* __restrict__ cnt,
                                              int* __restrict__ bsum, int N2)
{
    __shared__ int red[256];
    int t = threadIdx.x;
    int base = blockIdx.x * SCAN_CHUNK + t * 4;
    int s = 0;
    #pragma unroll
    for (int j = 0; j < 4; ++j) { int i = base + j; if (i < N2) s += cnt[i]; }
    red[t] = s; __syncthreads();
    for (int d = 128; d > 0; d >>= 1) {
        if (t < d) red[t] += red[t + d];
        __syncthreads();
    }
    if (t == 0) bsum[blockIdx.x] = red[0];
}

__global__ __launch_bounds__(128) void scan_b(int* __restrict__ bsum, int NB)
{
    __shared__ int part[128];
    int t = threadIdx.x;
    int v = (t < NB) ? bsum[t] : 0;
    part[t] = v; __syncthreads();
    for (int d = 1; d < 128; d <<= 1) {
        int w = (t >= d) ? part[t - d] : 0;
        __syncthreads();
        part[t] += w;
        __syncthreads();
    }
    if (t < NB) bsum[t] = part[t] - v;
}

__global__ __launch_bounds__(256) void scan_c(const int* __restrict__ cnt,
                                              const int* __restrict__ bsum,
                                              int* __restrict__ off,
                                              int N2, int NS, int ES)
{
    __shared__ int part[256];
    int t = threadIdx.x;
    int base = blockIdx.x * SCAN_CHUNK + t * 4;
    int c[4]; int s = 0;
    #pragma unroll
    for (int j = 0; j < 4; ++j) { int i = base + j; c[j] = (i < N2) ? cnt[i] : 0; s += c[j]; }
    part[t] = s; __syncthreads();
    for (int d = 1; d < 256; d <<= 1) {
        int w = (t >= d) ? part[t - d] : 0;
        __syncthreads();
        part[t] += w;
        __syncthreads();
    }
    int run = bsum[blockIdx.x] + part[t] - s;
    #pragma unroll
    for (int j = 0; j < 4; ++j) {
        int i = base + j;
        if (i < N2) off[i] = run - ((i >= NS) ? ES : 0);
        run += c[j];
    }
}

// ---------------------------------------------------------------------------
// scatter_sort2: dst-sorted ({src,dis} 8B + dst) for BOTH graphs.
// (sum zeroing lives in the DMA memset — cnt2|sum_u|sum_x are contiguous.)
// ---------------------------------------------------------------------------
__global__ __launch_bounds__(256) void scatter_sort2(
    const int* __restrict__ srcS, const int* __restrict__ dstS,
    const int* __restrict__ rankS, const int* __restrict__ offS,
    const float* __restrict__ disS,
    const int* __restrict__ srcA, const int* __restrict__ dstA,
    const int* __restrict__ rankA, const int* __restrict__ offA,
    const float* __restrict__ disA,
    uint2* __restrict__ sdS, int* __restrict__ sdstS,
    uint2* __restrict__ sdA, int* __restrict__ sdstA,
    int ES, int EA)
{
    int gtid = blockIdx.x * 256 + threadIdx.x;
    int gstr = gridDim.x * 256;
    int tot = ES + EA;
    for (int i = gtid; i < tot; i += gstr) {
        if (i < ES) {
            int d = dstS[i];
            int pos = offS[d] + rankS[i];
            uint2 v; v.x = (unsigned)srcS[i]; v.y = __float_as_uint(disS[i]);
            sdS[pos] = v;
            sdstS[pos] = d;
        } else {
            int e = i - ES;
            int d = dstA[e];
            int pos = offA[d] + rankA[e];
            uint2 v; v.x = (unsigned)srcA[e]; v.y = __float_as_uint(disA[e]);
            sdA[pos] = v;
            sdstA[pos] = d;
        }
    }
}

// ---------------------------------------------------------------------------
// edge_path: 3-layer edge MLP over sorted edges, segmented atomic emit.
// C1 = layer-1 chunk count; RS = row-table stride. UNCHANGED from R9.
// ---------------------------------------------------------------------------
template <int C1, int RS>
__device__ __forceinline__ void edge_path(
    const unsigned short* __restrict__ row_tab,
    const uint2* __restrict__ srcdis, const int* __restrict__ sdst,
    const float* __restrict__ ps,
    const unsigned short* WT,
    const float* __restrict__ b1, const float* __restrict__ b2,
    const float* __restrict__ b3,
    float* __restrict__ sums, int E, int bid0, int nb, int tid,
    unsigned short* Zbase)
{
    const unsigned short* W1 = WT;
    const unsigned short* W2 = WT + C1 * 2048;
    const unsigned short* W3 = WT + (C1 + 2) * 2048;

    int wid = tid >> 6, lane = tid & 63, m16 = lane & 15, q = lane >> 4;
    unsigned short* Zw = Zbase + wid * (16 * 72);

    float bb1[4], bb2[4], bb3[4];
    #pragma unroll
    for (int nt = 0; nt < 4; ++nt) {
        bb1[nt] = b1[nt * 16 + m16];
        bb2[nt] = b2[nt * 16 + m16];
        bb3[nt] = b3[nt * 16 + m16];
    }

    int T = E >> 5;
    for (int t = bid0 * 4 + wid; t < T; t += nb * 4) {
        int p0 = t * 32;
        int sp0 = p0 + ((m16 >> 2) << 3) + (m16 & 3);  // mt=0 A row
        int sp1 = sp0 + 4;                              // mt=1 A row
        uint2 sd0 = srcdis[sp0], sd1 = srcdis[sp1];
        int s0 = (int)sd0.x, s1 = (int)sd1.x;
        int pb = p0 + (q << 3);
        int4 dq0 = *(const int4*)(sdst + pb);
        int4 dq1 = *(const int4*)(sdst + pb + 4);
        int dseq[8] = {dq0.x, dq0.y, dq0.z, dq0.w, dq1.x, dq1.y, dq1.z, dq1.w};

        uint2 ep[2];
        ep[0].x = 0; ep[0].y = 0; ep[1].x = 0; ep[1].y = 0;
        if (q == 2) {   // pad lanes: {ps[d], dis, 1.0}
            int dA = sdst[sp0], dB = sdst[sp1];
            float2 pA = *(const float2*)(ps + 2 * dA);
            float2 pB = *(const float2*)(ps + 2 * dB);
            ep[0].x = pk2(pA.x, pA.y);
            ep[0].y = (unsigned)f2bf(__uint_as_float(sd0.y)) | (0x3F80u << 16);
            ep[1].x = pk2(pB.x, pB.y);
            ep[1].y = (unsigned)f2bf(__uint_as_float(sd1.y)) | (0x3F80u << 16);
        }

        FU Lb[2][C1];
        const unsigned short* rA = row_tab + (size_t)s0 * RS;
        const unsigned short* rB = row_tab + (size_t)s1 * RS;
        #pragma unroll
        for (int c = 0; c < C1; ++c) {
            int off = c * 32 + q * 8;
            bool valid = (c < C1 - 1) || (q < 2);
            if (valid) {
                Lb[0][c].v = *(const short8*)(rA + off);
                Lb[1][c].v = *(const short8*)(rB + off);
            } else {
                Lb[0][c].d[0] = ep[0].x; Lb[0][c].d[1] = ep[0].y; Lb[0][c].d[2] = 0; Lb[0][c].d[3] = 0;
                Lb[1][c].d[0] = ep[1].x; Lb[1][c].d[1] = ep[1].y; Lb[1][c].d[2] = 0; Lb[1][c].d[3] = 0;
            }
        }

        f32x4 acc1[2][4];
        #pragma unroll
        for (int mt = 0; mt < 2; ++mt)
            #pragma unroll
            for (int nt = 0; nt < 4; ++nt)
                acc1[mt][nt] = (f32x4){bb1[nt], bb1[nt], bb1[nt], bb1[nt]};
        #pragma unroll
        for (int c = 0; c < C1; ++c)
            #pragma unroll
            for (int nt = 0; nt < 4; ++nt) {
                short8 wf = *(const short8*)(W1 + ((c * 4 + nt) * 64 + lane) * 8);
                acc1[0][nt] = MFMA(Lb[0][c].v, wf, acc1[0][nt]);
                acc1[1][nt] = MFMA(Lb[1][c].v, wf, acc1[1][nt]);
            }

        f32x4 a3[2][4];
        #pragma unroll
        for (int mt = 0; mt < 2; ++mt) {
            ZTRANS(Zw, acc1[mt])
            FU A2[2];
            A2[0].v = *(const short8*)(Zw + m16 * 72 + 0 * 32 + q * 8);
            A2[1].v = *(const short8*)(Zw + m16 * 72 + 1 * 32 + q * 8);

            f32x4 a2[4];
            #pragma unroll
            for (int nt = 0; nt < 4; ++nt) {
                a2[nt] = (f32x4){bb2[nt], bb2[nt], bb2[nt], bb2[nt]};
                short8 w0 = *(const short8*)(W2 + ((0 * 4 + nt) * 64 + lane) * 8);
                short8 w1f = *(const short8*)(W2 + ((1 * 4 + nt) * 64 + lane) * 8);
                a2[nt] = MFMA(A2[0].v, w0, a2[nt]);
                a2[nt] = MFMA(A2[1].v, w1f, a2[nt]);
            }

            ZTRANS(Zw, a2)
            FU A3[2];
            A3[0].v = *(const short8*)(Zw + m16 * 72 + 0 * 32 + q * 8);
            A3[1].v = *(const short8*)(Zw + m16 * 72 + 1 * 32 + q * 8);

            #pragma unroll
            for (int nt = 0; nt < 4; ++nt) {
                a3[mt][nt] = (f32x4){bb3[nt], bb3[nt], bb3[nt], bb3[nt]};
                short8 w0 = *(const short8*)(W3 + ((0 * 4 + nt) * 64 + lane) * 8);
                short8 w1f = *(const short8*)(W3 + ((1 * 4 + nt) * 64 + lane) * 8);
                a3[mt][nt] = MFMA(A3[0].v, w0, a3[mt][nt]);
                a3[mt][nt] = MFMA(A3[1].v, w1f, a3[mt][nt]);
            }
        }

        // segmented emit: in-place run-merge, one base addr per edge
        #pragma unroll
        for (int j = 0; j < 8; ++j) {
            int mt = j >> 2, r = j & 3;
            bool merge = (j < 7) && (dseq[j] == dseq[j + 1]);
            if (merge) {
                int mt2 = (j + 1) >> 2, r2 = (j + 1) & 3;
                #pragma unroll
                for (int nt = 0; nt < 4; ++nt) a3[mt2][nt][r2] += a3[mt][nt][r];
            } else {
                float* pbase = sums + (size_t)dseq[j] * 64 + m16;
                #pragma unroll
                for (int nt = 0; nt < 4; ++nt)
                    unsafeAtomicAdd(pbase + nt * 16, a3[mt][nt][r]);
            }
        }
    }
}

// ---------------------------------------------------------------------------
// edges_mfma: UNIFORM blocks — every block runs its grid-stride share of
// s2s, then reloads WT (a2s weights) behind a barrier, then its share of
// a2s. One full residency round at grid 1024, no imbalance tail.
// ---------------------------------------------------------------------------
__global__ __launch_bounds__(256) void edges_mfma(
    const unsigned short* __restrict__ s_row, const unsigned short* __restrict__ a_row,
    const uint2* __restrict__ sdS, const int* __restrict__ sdstS,
    const uint2* __restrict__ sdA, const int* __restrict__ sdstA,
    const unsigned short* __restrict__ wtS, const unsigned short* __restrict__ wtA,
    const float* __restrict__ sb1, const float* __restrict__ sb2, const float* __restrict__ sb3,
    const float* __restrict__ ab1, const float* __restrict__ ab2, const float* __restrict__ ab3,
    const float* __restrict__ ps,
    float* __restrict__ sum_x, float* __restrict__ sum_u,
    int ES, int EA)
{
    __shared__ __align__(16) unsigned short WT[7 * 2048];
    __shared__ __align__(16) unsigned short Z[4][16 * 72];

    int tid = threadIdx.x, bid = blockIdx.x;
    int nb = gridDim.x;

    // phase 1: s2s
    for (int i = tid * 8; i < 7 * 2048; i += 256 * 8)
        *(short8*)(WT + i) = *(const short8*)(wtS + i);
    __syncthreads();
    edge_path<3, 80>(s_row, sdS, sdstS, ps, WT, sb1, sb2, sb3,
                     sum_x, ES, bid, nb, tid, &Z[0][0]);

    // phase 2: a2s (reload WT behind barriers)
    __syncthreads();
    for (int i = tid * 8; i < 5 * 2048; i += 256 * 8)
        *(short8*)(WT + i) = *(const short8*)(wtA + i);
    __syncthreads();
    edge_path<1, 16>(a_row, sdA, sdstA, ps, WT, ab1, ab2, ab3,
                     sum_u, EA, bid, nb, tid, &Z[0][0]);
}

// ---------------------------------------------------------------------------
// upd: fused gather (fp32 h/su/sxm/ps/x -> bf16 A-frags in-reg), K=224.
// W1 (28KB) in LDS; W2/W3 direct from global (L2-broadcast). As R15.
// ---------------------------------------------------------------------------
__global__ __launch_bounds__(256) void upd_mfma(
    const float* __restrict__ ps, const float* __restrict__ h,
    const float* __restrict__ x,
    const float* __restrict__ su, const float* __restrict__ sx,
    const int* __restrict__ cnt_s,
    const unsigned short* __restrict__ wtab,
    const float* __restrict__ b1, const float* __restrict__ b2,
    const float* __restrict__ b3,
    float* __restrict__ out, int NS)
{
    __shared__ __align__(16) unsigned short WT[7 * 2048];   // W1 only, 28 KB
    __shared__ __align__(16) unsigned short Z[4][16 * 72];

    int tid = threadIdx.x;
    for (int i = tid * 8; i < 7 * 2048; i += 256 * 8)
        *(short8*)(WT + i) = *(const short8*)(wtab + i);
    __syncthreads();

    const unsigned short* W1 = WT;
    const unsigned short* W2 = wtab + 7 * 2048;   // global, L2-resident
    const unsigned short* W3 = wtab + 9 * 2048;

    int wid = tid >> 6, lane = tid & 63, m16 = lane & 15, q = lane >> 4;
    unsigned short* Zw = &Z[wid][0];

    float bb1[4], bb2[4], bb3[4];
    #pragma unroll
    for (int nt = 0; nt < 4; ++nt) {
        bb1[nt] = b1[nt * 16 + m16];
        bb2[nt] = b2[nt * 16 + m16];
        bb3[nt] = b3[nt * 16 + m16];
    }

    int T = NS >> 4;
    for (int t = blockIdx.x * 4 + wid; t < T; t += gridDim.x * 4) {
        int n0 = t * 16;
        int n = n0 + m16;
        float rd = __builtin_amdgcn_rcpf(fmaxf((float)cnt_s[n], 1.0f));

        // A-frags: c=0,1 from h; 2,3 from su; 4,5 from sx*rd; 6 piecewise
        FU A[7];
        const float* hp = h + (size_t)n * 64;
        const float* sup = su + (size_t)n * 64;
        const float* sxp = sx + (size_t)n * 64;
        #pragma unroll
        for (int c = 0; c < 6; ++c) {
            const float* src = (c < 2) ? hp : (c < 4) ? sup : sxp;
            int base = (c & 1) * 32 + q * 8;
            float4 f0 = *(const float4*)(src + base);
            float4 f1 = *(const float4*)(src + base + 4);
            if (c >= 4) {
                f0.x *= rd; f0.y *= rd; f0.z *= rd; f0.w *= rd;
                f1.x *= rd; f1.y *= rd; f1.z *= rd; f1.w *= rd;
            }
            A[c].d[0] = pk2(f0.x, f0.y); A[c].d[1] = pk2(f0.z, f0.w);
            A[c].d[2] = pk2(f1.x, f1.y); A[c].d[3] = pk2(f1.z, f1.w);
        }
        A[6].d[0] = 0; A[6].d[1] = 0; A[6].d[2] = 0; A[6].d[3] = 0;
        if (q == 0) {
            float2 pp = *(const float2*)(ps + 2 * n);
            float4 x0 = *(const float4*)(x + 8 * n);
            float2 x1 = *(const float2*)(x + 8 * n + 4);
            A[6].d[0] = pk2(pp.x, pp.y);
            A[6].d[1] = pk2(x0.x, x0.y);
            A[6].d[2] = pk2(x0.z, x0.w);
            A[6].d[3] = pk2(x1.x, x1.y);
        } else if (q == 1) {
            float2 x2 = *(const float2*)(x + 8 * n + 6);
            A[6].d[0] = pk2(x2.x, x2.y);
        }

        f32x4 acc1[4];
        #pragma unroll
        for (int nt = 0; nt < 4; ++nt)
            acc1[nt] = (f32x4){bb1[nt], bb1[nt], bb1[nt], bb1[nt]};
        #pragma unroll
        for (int c = 0; c < 7; ++c)
            #pragma unroll
            for (int nt = 0; nt < 4; ++nt) {
                short8 wf = *(const short8*)(W1 + ((c * 4 + nt) * 64 + lane) * 8);
                acc1[nt] = MFMA(A[c].v, wf, acc1[nt]);
            }

        ZTRANS(Zw, acc1)
        FU A2[2];
        A2[0].v = *(const short8*)(Zw + m16 * 72 + 0 * 32 + q * 8);
        A2[1].v = *(const short8*)(Zw + m16 * 72 + 1 * 32 + q * 8);

        f32x4 a2[4];
        #pragma unroll
        for (int nt = 0; nt < 4; ++nt) {
            a2[nt] = (f32x4){bb2[nt], bb2[nt], bb2[nt], bb2[nt]};
            short8 w0 = *(const short8*)(W2 + ((0 * 4 + nt) * 64 + lane) * 8);
            short8 w1f = *(const short8*)(W2 + ((1 * 4 + nt) * 64 + lane) * 8);
            a2[nt] = MFMA(A2[0].v, w0, a2[nt]);
            a2[nt] = MFMA(A2[1].v, w1f, a2[nt]);
        }

        ZTRANS(Zw, a2)
        FU A3[2];
        A3[0].v = *(const short8*)(Zw + m16 * 72 + 0 * 32 + q * 8);
        A3[1].v = *(const short8*)(Zw + m16 * 72 + 1 * 32 + q * 8);

        f32x4 a3[4];
        #pragma unroll
        for (int nt = 0; nt < 4; ++nt) {
            a3[nt] = (f32x4){bb3[nt], bb3[nt], bb3[nt], bb3[nt]};
            short8 w0 = *(const short8*)(W3 + ((0 * 4 + nt) * 64 + lane) * 8);
            short8 w1f = *(const short8*)(W3 + ((1 * 4 + nt) * 64 + lane) * 8);
            a3[nt] = MFMA(A3[0].v, w0, a3[nt]);
            a3[nt] = MFMA(A3[1].v, w1f, a3[nt]);
        }

        #pragma unroll
        for (int nt = 0; nt < 4; ++nt)
            #pragma unroll
            for (int r = 0; r < 4; ++r)
                out[(size_t)(n0 + (q << 2) + r) * 64 + nt * 16 + m16] = a3[nt][r];
    }
}

extern "C" void kernel_launch(void* const* d_in, const int* in_sizes, int n_in,
                              void* d_out, int out_size, void* d_ws, size_t ws_size,
                              hipStream_t stream) {
    const float* pos_state  = (const float*)d_in[0];
    const float* pos_action = (const float*)d_in[1];
    const float* h          = (const float*)d_in[2];
    const float* x          = (const float*)d_in[3];
    const float* u          = (const float*)d_in[4];
    const int*   a2s_src    = (const int*)d_in[5];
    const int*   a2s_dst    = (const int*)d_in[6];
    const float* a2s_dis    = (const float*)d_in[7];
    const int*   s2s_src    = (const int*)d_in[8];
    const int*   s2s_dst    = (const int*)d_in[9];
    const float* s2s_dis    = (const float*)d_in[10];
    const float* u2h_w1 = (const float*)d_in[11]; const float* u2h_b1 = (const float*)d_in[12];
    const float* u2h_w2 = (const float*)d_in[13]; const float* u2h_b2 = (const float*)d_in[14];
    const float* u2h_w3 = (const float*)d_in[15]; const float* u2h_b3 = (const float*)d_in[16];
    const float* x2h_w1 = (const float*)d_in[17]; const float* x2h_b1 = (const float*)d_in[18];
    const float* x2h_w2 = (const float*)d_in[19]; const float* x2h_b2 = (const float*)d_in[20];
    const float* x2h_w3 = (const float*)d_in[21]; const float* x2h_b3 = (const float*)d_in[22];
    const float* upd_w1 = (const float*)d_in[23]; const float* upd_b1 = (const float*)d_in[24];
    const float* upd_w2 = (const float*)d_in[25]; const float* upd_b2 = (const float*)d_in[26];
    const float* upd_w3 = (const float*)d_in[27]; const float* upd_b3 = (const float*)d_in[28];

    int NS = in_sizes[0] / 2;
    int NA = in_sizes[1] / 2;
    int EA = in_sizes[5];
    int ES = in_sizes[8];
    int N2 = 2 * NS;
    int NB = (N2 + SCAN_CHUNK - 1) / SCAN_CHUNK;

    char* p = (char*)d_ws;
    int*   cnt2  = (int*)p;            p += (size_t)N2 * 4;       // cnt_s | cnt_a
    float* sum_u = (float*)p;          p += (size_t)NS * 64 * 4;
    float* sum_x = (float*)p;          p += (size_t)NS * 64 * 4;
    size_t zbytes = (size_t)(p - (char*)d_ws);                    // memset: cnt2 + sums (contiguous)
    int*   off2   = (int*)p;           p += (size_t)N2 * 4;
    int*   rank_s = (int*)p;           p += (size_t)ES * 4;
    int*   rank_a = (int*)p;           p += (size_t)EA * 4;
    uint2* sd_s   = (uint2*)p;         p += (size_t)ES * 8;       // {src,dis}
    int*   sdst_s = (int*)p;           p += (size_t)ES * 4;
    uint2* sd_a   = (uint2*)p;         p += (size_t)EA * 8;
    int*   sdst_a = (int*)p;           p += (size_t)EA * 4;
    unsigned short* s_row  = (unsigned short*)p; p += (size_t)NS * 80 * 2;
    unsigned short* a_row  = (unsigned short*)p; p += (size_t)NA * 16 * 2;
    int*   bsum   = (int*)p;           p += 128 * 4;
    unsigned short* wtab_s = (unsigned short*)p; p += 7 * 2048 * 2;
    unsigned short* wtab_a = (unsigned short*)p; p += 5 * 2048 * 2;
    unsigned short* wtab_u = (unsigned short*)p; p += 11 * 2048 * 2;
    (void)ws_size;

    int* cnt_s = cnt2;
    int* cnt_a = cnt2 + NS;
    int* off_s = off2;
    int* off_a = off2 + NS;

    hipMemsetAsync(d_ws, 0, zbytes, stream);

    const int MAINB = 2048;
    prep1<<<MAINB + 24, 256, 0, stream>>>(pos_state, pos_action, h, x, u,
                                          s2s_dst, a2s_dst, s_row, a_row,
                                          cnt_s, rank_s, cnt_a, rank_a,
                                          x2h_w1, x2h_w2, x2h_w3,
                                          u2h_w1, u2h_w2, u2h_w3,
                                          upd_w1, upd_w2, upd_w3,
                                          wtab_s, wtab_a, wtab_u,
                                          NS, NA, ES, EA, MAINB);
    scan_a<<<NB, 256, 0, stream>>>(cnt2, bsum, N2);
    scan_b<<<1, 128, 0, stream>>>(bsum, NB);
    scan_c<<<NB, 256, 0, stream>>>(cnt2, bsum, off2, N2, NS, ES);
    scatter_sort2<<<2048, 256, 0, stream>>>(s2s_src, s2s_dst, rank_s, off_s, s2s_dis,
                                            a2s_src, a2s_dst, rank_a, off_a, a2s_dis,
                                            sd_s, sdst_s, sd_a, sdst_a,
                                            ES, EA);
    edges_mfma<<<1024, 256, 0, stream>>>(s_row, a_row,
                                         sd_s, sdst_s, sd_a, sdst_a,
                                         wtab_s, wtab_a,
                                         x2h_b1, x2h_b2, x2h_b3,
                                         u2h_b1, u2h_b2, u2h_b3,
                                         pos_state, sum_x, sum_u,
                                         ES, EA);
    upd_mfma<<<784, 256, 0, stream>>>(pos_state, h, x, sum_u, sum_x, cnt_s,
                                      wtab_u, upd_b1, upd_b2, upd_b3,
                                      (float*)d_out, NS);
}

// Round 8
// 417.567 us; speedup vs baseline: 1.1447x; 1.1447x over previous
//
#include <hip/hip_runtime.h>
#include <hip/hip_bf16.h>

// R17: restore the exact global best (R9/R0 config, 423-429 us measured).
// Session ledger for edges_mfma: R10 launch_bounds->spills(236), R11
// setprio->VGPR132(216), R12 chunk+swizzle->128(163), R13 grid1024(156),
// R14 grid2048(153), R16 uniform-2phase->132(198). Conclusion: edge_path
// codegen sits on a razor-edge 124-VGPR allocation only this exact source
// produces; grid sweep is a clean U minimized at 1536/1120; kernel is
// serial-chain latency-bound (dur*VALUBusy ~= 7700 across all 7 configs).
// R15's non-edges tweaks measured neutral-to-negative -> also reverted.

typedef __attribute__((ext_vector_type(8))) short short8;
typedef __attribute__((ext_vector_type(4))) float f32x4;

#define MFMA(a, b, c) __builtin_amdgcn_mfma_f32_16x16x32_bf16(a, b, c, 0, 0, 0)

union FU { short8 v; unsigned int d[4]; unsigned short us[8]; };

__device__ __forceinline__ unsigned short f2bf(float f) {
    unsigned u = __float_as_uint(f);
    u += 0x7fffu + ((u >> 16) & 1u);   // RNE (data NaN-free)
    return (unsigned short)(u >> 16);
}
__device__ __forceinline__ unsigned int pk2(float a, float b) {
    float2 t; t.x = a; t.y = b;
    union { __hip_bfloat162 h; unsigned int u; } c;
    c.h = __float22bfloat162_rn(t);     // v_cvt_pk_bf16_f32
    return c.u;
}
__device__ __forceinline__ float tanh_fast(float xv) {
    float t = __builtin_amdgcn_exp2f(xv * 2.8853900817779268f); // 2*log2(e)
    return 1.0f - 2.0f * __builtin_amdgcn_rcpf(t + 1.0f);
}

// Build weight fragment tables in GLOBAL memory (once).
// frag(c,nt): lane holds W[k = c*32 + (lane>>4)*8 + j][n = nt*16 + (lane&15)].
template <typename KM>
__device__ void build_gfrags(const float* __restrict__ w, unsigned short* dst,
                             int nchunks, int gtid, int gstr, KM km) {
    int total = nchunks * 4 * 64;
    for (int f = gtid; f < total; f += gstr) {
        int lv = f & 63, nt = (f >> 6) & 3, c = f >> 8;
        int n = nt * 16 + (lv & 15);
        int kb = c * 32 + ((lv >> 4) << 3);
        unsigned short* o = dst + f * 8;
        #pragma unroll
        for (int j = 0; j < 8; ++j) {
            int sk = km(kb + j);
            o[j] = (sk >= 0) ? f2bf(w[sk * 64 + n]) : (unsigned short)0;
        }
    }
}

#define PERM_KM [](int k) -> int { return (k >> 2) + 16 * (k & 3); }

// C-layout (lane q,m16 holds row=q*4+r, feat=nt*16+m16) -> Zb[row][kpos],
// kpos = 4*m16 + nt; row stride 72 elems.
#define ZTRANS(Zw, accv)                                                       \
    _Pragma("unroll")                                                          \
    for (int r = 0; r < 4; ++r) {                                              \
        uint2 pv;                                                              \
        pv.x = pk2(tanh_fast(accv[0][r]), tanh_fast(accv[1][r]));              \
        pv.y = pk2(tanh_fast(accv[2][r]), tanh_fast(accv[3][r]));              \
        *(uint2*)((Zw) + ((q << 2) + r) * 72 + (m16 << 2)) = pv;               \
    }

// ---------------------------------------------------------------------------
// prep1: bf16 row tables (vectorized) + per-dst counts & ranks + wtab build
// ---------------------------------------------------------------------------
__global__ __launch_bounds__(256) void prep1(
    const float* __restrict__ ps, const float* __restrict__ pa,
    const float* __restrict__ h, const float* __restrict__ x,
    const float* __restrict__ u,
    const int* __restrict__ s2s_dst, const int* __restrict__ a2s_dst,
    unsigned short* __restrict__ s_row, unsigned short* __restrict__ a_row,
    int* __restrict__ cnt_s, int* __restrict__ rank_s,
    int* __restrict__ cnt_a, int* __restrict__ rank_a,
    const float* __restrict__ s_w1, const float* __restrict__ s_w2, const float* __restrict__ s_w3,
    const float* __restrict__ a_w1, const float* __restrict__ a_w2, const float* __restrict__ a_w3,
    const float* __restrict__ u_w1, const float* __restrict__ u_w2, const float* __restrict__ u_w3,
    unsigned short* __restrict__ ts, unsigned short* __restrict__ ta,
    unsigned short* __restrict__ tu,
    int NS, int NA, int ES, int EA, int MAINB)
{
    int bid = blockIdx.x;
    if (bid >= MAINB) {
        int gtid = (bid - MAINB) * 256 + threadIdx.x;
        int gstr = (gridDim.x - MAINB) * 256;
        build_gfrags(s_w1, ts, 3, gtid, gstr, [](int k) -> int {
            if (k < 2)   return k;          // ps_src
            if (k < 74)  return k + 3;      // x, h
            if (k < 80)  return -2;
            if (k < 82)  return k - 78;     // ps_dst
            if (k == 82) return 4;          // dis
            return -2; });
        build_gfrags(s_w2, ts + 3 * 2048, 2, gtid, gstr, PERM_KM);
        build_gfrags(s_w3, ts + 5 * 2048, 2, gtid, gstr, PERM_KM);
        build_gfrags(a_w1, ta, 1, gtid, gstr, [](int k) -> int {
            if (k < 2)   return k;          // pa
            if (k < 10)  return k + 3;      // u
            if (k < 16)  return -2;
            if (k < 18)  return k - 14;     // ps_dst
            if (k == 18) return 4;          // dis
            return -2; });
        build_gfrags(a_w2, ta + 1 * 2048, 2, gtid, gstr, PERM_KM);
        build_gfrags(a_w3, ta + 3 * 2048, 2, gtid, gstr, PERM_KM);
        // upd W1 with K-order [h(64) | su(64) | sxm(64) | ps(2), x(8)]
        build_gfrags(u_w1, tu, 7, gtid, gstr, [](int k) -> int {
            if (k < 192) return k + 2;      // h, su, sxm (orig 2..193)
            if (k < 194) return k - 192;    // ps (orig 0,1)
            if (k < 202) return k;          // x (orig 194..201)
            return -2; });
        build_gfrags(u_w2, tu + 7 * 2048, 2, gtid, gstr, PERM_KM);
        build_gfrags(u_w3, tu + 9 * 2048, 2, gtid, gstr, PERM_KM);
        return;
    }

    // padded index spaces: s_row NS*32 (20 active of 32), a_row NA*4, ranks
    int R0 = NS * 32, R1 = R0 + NA * 4, R2 = R1 + ES, R3 = R2 + EA;
    for (int i = bid * 256 + threadIdx.x; i < R3; i += MAINB * 256) {
        if (i < R0) {
            int n = i >> 5, kq = i & 31;
            if (kq < 20) {
                int k0 = kq << 2;
                float f[4];
                #pragma unroll
                for (int j = 0; j < 4; ++j) {
                    int k = k0 + j;
                    f[j] = (k < 2) ? ps[n * 2 + k] : (k < 10) ? x[n * 8 + k - 2]
                         : (k < 74) ? h[n * 64 + k - 10] : 0.f;
                }
                uint2 o; o.x = pk2(f[0], f[1]); o.y = pk2(f[2], f[3]);
                *(uint2*)&s_row[(size_t)n * 80 + k0] = o;
            }
        } else if (i < R1) {
            int j2 = i - R0; int a = j2 >> 2, kq = j2 & 3;
            int k0 = kq << 2;
            float f[4];
            #pragma unroll
            for (int j = 0; j < 4; ++j) {
                int k = k0 + j;
                f[j] = (k < 2) ? pa[a * 2 + k] : (k < 10) ? u[a * 8 + k - 2] : 0.f;
            }
            uint2 o; o.x = pk2(f[0], f[1]); o.y = pk2(f[2], f[3]);
            *(uint2*)&a_row[(size_t)a * 16 + k0] = o;
        } else if (i < R2) {
            int e = i - R1;
            rank_s[e] = atomicAdd(&cnt_s[s2s_dst[e]], 1);
        } else {
            int e = i - R2;
            rank_a[e] = atomicAdd(&cnt_a[a2s_dst[e]], 1);
        }
    }
}

// ---------------------------------------------------------------------------
// 3-phase multi-block exclusive scan over concatenated [cnt_s | cnt_a].
// ---------------------------------------------------------------------------
#define SCAN_CHUNK 1024

__global__ __launch_bounds__(256) void scan_a(const int* __restrict__ cnt,
                                              int* __restrict__ bsum, int N2)
{
    __shared__ int red[256];
    int t = threadIdx.x;
    int base = blockIdx.x * SCAN_CHUNK + t * 4;
    int s = 0;
    #pragma unroll
    for (int j = 0; j < 4; ++j) { int i = base + j; if (i < N2) s += cnt[i]; }
    red[t] = s; __syncthreads();
    for (int d = 128; d > 0; d >>= 1) {
        if (t < d) red[t] += red[t + d];
        __syncthreads();
    }
    if (t == 0) bsum[blockIdx.x] = red[0];
}

__global__ __launch_bounds__(128) void scan_b(int* __restrict__ bsum, int NB)
{
    __shared__ int part[128];
    int t = threadIdx.x;
    int v = (t < NB) ? bsum[t] : 0;
    part[t] = v; __syncthreads();
    for (int d = 1; d < 128; d <<= 1) {
        int w = (t >= d) ? part[t - d] : 0;
        __syncthreads();
        part[t] += w;
        __syncthreads();
    }
    if (t < NB) bsum[t] = part[t] - v;
}

__global__ __launch_bounds__(256) void scan_c(const int* __restrict__ cnt,
                                              const int* __restrict__ bsum,
                                              int* __restrict__ off,
                                              int N2, int NS, int ES)
{
    __shared__ int part[256];
    int t = threadIdx.x;
    int base = blockIdx.x * SCAN_CHUNK + t * 4;
    int c[4]; int s = 0;
    #pragma unroll
    for (int j = 0; j < 4; ++j) { int i = base + j; c[j] = (i < N2) ? cnt[i] : 0; s += c[j]; }
    part[t] = s; __syncthreads();
    for (int d = 1; d < 256; d <<= 1) {
        int w = (t >= d) ? part[t - d] : 0;
        __syncthreads();
        part[t] += w;
        __syncthreads();
    }
    int run = bsum[blockIdx.x] + part[t] - s;
    #pragma unroll
    for (int j = 0; j < 4; ++j) {
        int i = base + j;
        if (i < N2) off[i] = run - ((i >= NS) ? ES : 0);
        run += c[j];
    }
}

// ---------------------------------------------------------------------------
// scatter_sort2: dst-sorted ({src,dis} 8B + dst) for BOTH graphs,
// plus zeroing of sum_u/sum_x (contiguous NS*128 floats).
// ---------------------------------------------------------------------------
__global__ __launch_bounds__(256) void scatter_sort2(
    const int* __restrict__ srcS, const int* __restrict__ dstS,
    const int* __restrict__ rankS, const int* __restrict__ offS,
    const float* __restrict__ disS,
    const int* __restrict__ srcA, const int* __restrict__ dstA,
    const int* __restrict__ rankA, const int* __restrict__ offA,
    const float* __restrict__ disA,
    uint2* __restrict__ sdS, int* __restrict__ sdstS,
    uint2* __restrict__ sdA, int* __restrict__ sdstA,
    float* __restrict__ sums, int ES, int EA, int NZ4)
{
    int gtid = blockIdx.x * 256 + threadIdx.x;
    int gstr = gridDim.x * 256;
    // zero sum_u | sum_x (NZ4 float4's)
    for (int i = gtid; i < NZ4; i += gstr)
        ((f32x4*)sums)[i] = (f32x4){0.f, 0.f, 0.f, 0.f};
    int tot = ES + EA;
    for (int i = gtid; i < tot; i += gstr) {
        if (i < ES) {
            int d = dstS[i];
            int pos = offS[d] + rankS[i];
            uint2 v; v.x = (unsigned)srcS[i]; v.y = __float_as_uint(disS[i]);
            sdS[pos] = v;
            sdstS[pos] = d;
        } else {
            int e = i - ES;
            int d = dstA[e];
            int pos = offA[d] + rankA[e];
            uint2 v; v.x = (unsigned)srcA[e]; v.y = __float_as_uint(disA[e]);
            sdA[pos] = v;
            sdstA[pos] = d;
        }
    }
}

// ---------------------------------------------------------------------------
// edge_path: 3-layer edge MLP over sorted edges, segmented atomic emit.
// C1 = layer-1 chunk count; RS = row-table stride.
// ---------------------------------------------------------------------------
template <int C1, int RS>
__device__ __forceinline__ void edge_path(
    const unsigned short* __restrict__ row_tab,
    const uint2* __restrict__ srcdis, const int* __restrict__ sdst,
    const float* __restrict__ ps,
    const unsigned short* WT,
    const float* __restrict__ b1, const float* __restrict__ b2,
    const float* __restrict__ b3,
    float* __restrict__ sums, int E, int bid0, int nb, int tid,
    unsigned short* Zbase)
{
    const unsigned short* W1 = WT;
    const unsigned short* W2 = WT + C1 * 2048;
    const unsigned short* W3 = WT + (C1 + 2) * 2048;

    int wid = tid >> 6, lane = tid & 63, m16 = lane & 15, q = lane >> 4;
    unsigned short* Zw = Zbase + wid * (16 * 72);

    float bb1[4], bb2[4], bb3[4];
    #pragma unroll
    for (int nt = 0; nt < 4; ++nt) {
        bb1[nt] = b1[nt * 16 + m16];
        bb2[nt] = b2[nt * 16 + m16];
        bb3[nt] = b3[nt * 16 + m16];
    }

    int T = E >> 5;
    for (int t = bid0 * 4 + wid; t < T; t += nb * 4) {
        int p0 = t * 32;
        int sp0 = p0 + ((m16 >> 2) << 3) + (m16 & 3);  // mt=0 A row
        int sp1 = sp0 + 4;                              // mt=1 A row
        uint2 sd0 = srcdis[sp0], sd1 = srcdis[sp1];
        int s0 = (int)sd0.x, s1 = (int)sd1.x;
        int pb = p0 + (q << 3);
        int4 dq0 = *(const int4*)(sdst + pb);
        int4 dq1 = *(const int4*)(sdst + pb + 4);
        int dseq[8] = {dq0.x, dq0.y, dq0.z, dq0.w, dq1.x, dq1.y, dq1.z, dq1.w};

        uint2 ep[2];
        ep[0].x = 0; ep[0].y = 0; ep[1].x = 0; ep[1].y = 0;
        if (q == 2) {   // pad lanes: {ps[d], dis, 1.0}
            int dA = sdst[sp0], dB = sdst[sp1];
            float2 pA = *(const float2*)(ps + 2 * dA);
            float2 pB = *(const float2*)(ps + 2 * dB);
            ep[0].x = pk2(pA.x, pA.y);
            ep[0].y = (unsigned)f2bf(__uint_as_float(sd0.y)) | (0x3F80u << 16);
            ep[1].x = pk2(pB.x, pB.y);
            ep[1].y = (unsigned)f2bf(__uint_as_float(sd1.y)) | (0x3F80u << 16);
        }

        FU Lb[2][C1];
        const unsigned short* rA = row_tab + (size_t)s0 * RS;
        const unsigned short* rB = row_tab + (size_t)s1 * RS;
        #pragma unroll
        for (int c = 0; c < C1; ++c) {
            int off = c * 32 + q * 8;
            bool valid = (c < C1 - 1) || (q < 2);
            if (valid) {
                Lb[0][c].v = *(const short8*)(rA + off);
                Lb[1][c].v = *(const short8*)(rB + off);
            } else {
                Lb[0][c].d[0] = ep[0].x; Lb[0][c].d[1] = ep[0].y; Lb[0][c].d[2] = 0; Lb[0][c].d[3] = 0;
                Lb[1][c].d[0] = ep[1].x; Lb[1][c].d[1] = ep[1].y; Lb[1][c].d[2] = 0; Lb[1][c].d[3] = 0;
            }
        }

        f32x4 acc1[2][4];
        #pragma unroll
        for (int mt = 0; mt < 2; ++mt)
            #pragma unroll
            for (int nt = 0; nt < 4; ++nt)
                acc1[mt][nt] = (f32x4){bb1[nt], bb1[nt], bb1[nt], bb1[nt]};
        #pragma unroll
        for (int c = 0; c < C1; ++c)
            #pragma unroll
            for (int nt = 0; nt < 4; ++nt) {
                short8 wf = *(const short8*)(W1 + ((c * 4 + nt) * 64 + lane) * 8);
                acc1[0][nt] = MFMA(Lb[0][c].v, wf, acc1[0][nt]);
                acc1[1][nt] = MFMA(Lb[1][c].v, wf, acc1[1][nt]);
            }

        f32x4 a3[2][4];
        #pragma unroll
        for (int mt = 0; mt < 2; ++mt) {
            ZTRANS(Zw, acc1[mt])
            FU A2[2];
            A2[0].v = *(const short8*)(Zw + m16 * 72 + 0 * 32 + q * 8);
            A2[1].v = *(const short8*)(Zw + m16 * 72 + 1 * 32 + q * 8);

            f32x4 a2[4];
            #pragma unroll
            for (int nt = 0; nt < 4; ++nt) {
                a2[nt] = (f32x4){bb2[nt], bb2[nt], bb2[nt], bb2[nt]};
                short8 w0 = *(const short8*)(W2 + ((0 * 4 + nt) * 64 + lane) * 8);
                short8 w1f = *(const short8*)(W2 + ((1 * 4 + nt) * 64 + lane) * 8);
                a2[nt] = MFMA(A2[0].v, w0, a2[nt]);
                a2[nt] = MFMA(A2[1].v, w1f, a2[nt]);
            }

            ZTRANS(Zw, a2)
            FU A3[2];
            A3[0].v = *(const short8*)(Zw + m16 * 72 + 0 * 32 + q * 8);
            A3[1].v = *(const short8*)(Zw + m16 * 72 + 1 * 32 + q * 8);

            #pragma unroll
            for (int nt = 0; nt < 4; ++nt) {
                a3[mt][nt] = (f32x4){bb3[nt], bb3[nt], bb3[nt], bb3[nt]};
                short8 w0 = *(const short8*)(W3 + ((0 * 4 + nt) * 64 + lane) * 8);
                short8 w1f = *(const short8*)(W3 + ((1 * 4 + nt) * 64 + lane) * 8);
                a3[mt][nt] = MFMA(A3[0].v, w0, a3[mt][nt]);
                a3[mt][nt] = MFMA(A3[1].v, w1f, a3[mt][nt]);
            }
        }

        // segmented emit: in-place run-merge, one base addr per edge
        #pragma unroll
        for (int j = 0; j < 8; ++j) {
            int mt = j >> 2, r = j & 3;
            bool merge = (j < 7) && (dseq[j] == dseq[j + 1]);
            if (merge) {
                int mt2 = (j + 1) >> 2, r2 = (j + 1) & 3;
                #pragma unroll
                for (int nt = 0; nt < 4; ++nt) a3[mt2][nt][r2] += a3[mt][nt][r];
            } else {
                float* pbase = sums + (size_t)dseq[j] * 64 + m16;
                #pragma unroll
                for (int nt = 0; nt < 4; ++nt)
                    unsafeAtomicAdd(pbase + nt * 16, a3[mt][nt][r]);
            }
        }
    }
}

// ---------------------------------------------------------------------------
// edges_mfma: s2s (blocks < SPLIT) and a2s (blocks >= SPLIT) in one dispatch.
// ---------------------------------------------------------------------------
__global__ __launch_bounds__(256) void edges_mfma(
    const unsigned short* __restrict__ s_row, const unsigned short* __restrict__ a_row,
    const uint2* __restrict__ sdS, const int* __restrict__ sdstS,
    const uint2* __restrict__ sdA, const int* __restrict__ sdstA,
    const unsigned short* __restrict__ wtS, const unsigned short* __restrict__ wtA,
    const float* __restrict__ sb1, const float* __restrict__ sb2, const float* __restrict__ sb3,
    const float* __restrict__ ab1, const float* __restrict__ ab2, const float* __restrict__ ab3,
    const float* __restrict__ ps,
    float* __restrict__ sum_x, float* __restrict__ sum_u,
    int ES, int EA, int SPLIT)
{
    __shared__ __align__(16) unsigned short WT[7 * 2048];
    __shared__ __align__(16) unsigned short Z[4][16 * 72];

    int tid = threadIdx.x, bid = blockIdx.x;
    bool is_s = bid < SPLIT;
    const unsigned short* wt = is_s ? wtS : wtA;
    int wtn = is_s ? 7 * 2048 : 5 * 2048;
    for (int i = tid * 8; i < wtn; i += 256 * 8)
        *(short8*)(WT + i) = *(const short8*)(wt + i);
    __syncthreads();

    if (is_s)
        edge_path<3, 80>(s_row, sdS, sdstS, ps, WT, sb1, sb2, sb3,
                         sum_x, ES, bid, SPLIT, tid, &Z[0][0]);
    else
        edge_path<1, 16>(a_row, sdA, sdstA, ps, WT, ab1, ab2, ab3,
                         sum_u, EA, bid - SPLIT, gridDim.x - SPLIT, tid, &Z[0][0]);
}

// ---------------------------------------------------------------------------
// upd: fused gather (fp32 h/su/sxm/ps/x -> bf16 A-frags in-reg), K=224.
// Feature order matches prep1's permuted u_w1: [h | su | sxm | ps, x].
// ---------------------------------------------------------------------------
__global__ __launch_bounds__(256) void upd_mfma(
    const float* __restrict__ ps, const float* __restrict__ h,
    const float* __restrict__ x,
    const float* __restrict__ su, const float* __restrict__ sx,
    const int* __restrict__ cnt_s,
    const unsigned short* __restrict__ wtab,
    const float* __restrict__ b1, const float* __restrict__ b2,
    const float* __restrict__ b3,
    float* __restrict__ out, int NS)
{
    __shared__ __align__(16) unsigned short WT[11 * 2048];  // 44 KB
    __shared__ __align__(16) unsigned short Z[4][16 * 72];

    int tid = threadIdx.x;
    for (int i = tid * 8; i < 11 * 2048; i += 256 * 8)
        *(short8*)(WT + i) = *(const short8*)(wtab + i);
    __syncthreads();

    const unsigned short* W1 = WT;
    const unsigned short* W2 = WT + 7 * 2048;
    const unsigned short* W3 = WT + 9 * 2048;

    int wid = tid >> 6, lane = tid & 63, m16 = lane & 15, q = lane >> 4;
    unsigned short* Zw = &Z[wid][0];

    float bb1[4], bb2[4], bb3[4];
    #pragma unroll
    for (int nt = 0; nt < 4; ++nt) {
        bb1[nt] = b1[nt * 16 + m16];
        bb2[nt] = b2[nt * 16 + m16];
        bb3[nt] = b3[nt * 16 + m16];
    }

    int T = NS >> 4;
    for (int t = blockIdx.x * 4 + wid; t < T; t += gridDim.x * 4) {
        int n0 = t * 16;
        int n = n0 + m16;
        float rd = __builtin_amdgcn_rcpf(fmaxf((float)cnt_s[n], 1.0f));

        // A-frags: c=0,1 from h; 2,3 from su; 4,5 from sx*rd; 6 piecewise
        FU A[7];
        const float* hp = h + (size_t)n * 64;
        const float* sup = su + (size_t)n * 64;
        const float* sxp = sx + (size_t)n * 64;
        #pragma unroll
        for (int c = 0; c < 6; ++c) {
            const float* src = (c < 2) ? hp : (c < 4) ? sup : sxp;
            int base = (c & 1) * 32 + q * 8;
            float4 f0 = *(const float4*)(src + base);
            float4 f1 = *(const float4*)(src + base + 4);
            if (c >= 4) {
                f0.x *= rd; f0.y *= rd; f0.z *= rd; f0.w *= rd;
                f1.x *= rd; f1.y *= rd; f1.z *= rd; f1.w *= rd;
            }
            A[c].d[0] = pk2(f0.x, f0.y); A[c].d[1] = pk2(f0.z, f0.w);
            A[c].d[2] = pk2(f1.x, f1.y); A[c].d[3] = pk2(f1.z, f1.w);
        }
        A[6].d[0] = 0; A[6].d[1] = 0; A[6].d[2] = 0; A[6].d[3] = 0;
        if (q == 0) {
            float2 pp = *(const float2*)(ps + 2 * n);
            float4 x0 = *(const float4*)(x + 8 * n);
            float2 x1 = *(const float2*)(x + 8 * n + 4);
            A[6].d[0] = pk2(pp.x, pp.y);
            A[6].d[1] = pk2(x0.x, x0.y);
            A[6].d[2] = pk2(x0.z, x0.w);
            A[6].d[3] = pk2(x1.x, x1.y);
        } else if (q == 1) {
            float2 x2 = *(const float2*)(x + 8 * n + 6);
            A[6].d[0] = pk2(x2.x, x2.y);
        }

        f32x4 acc1[4];
        #pragma unroll
        for (int nt = 0; nt < 4; ++nt)
            acc1[nt] = (f32x4){bb1[nt], bb1[nt], bb1[nt], bb1[nt]};
        #pragma unroll
        for (int c = 0; c < 7; ++c)
            #pragma unroll
            for (int nt = 0; nt < 4; ++nt) {
                short8 wf = *(const short8*)(W1 + ((c * 4 + nt) * 64 + lane) * 8);
                acc1[nt] = MFMA(A[c].v, wf, acc1[nt]);
            }

        ZTRANS(Zw, acc1)
        FU A2[2];
        A2[0].v = *(const short8*)(Zw + m16 * 72 + 0 * 32 + q * 8);
        A2[1].v = *(const short8*)(Zw + m16 * 72 + 1 * 32 + q * 8);

        f32x4 a2[4];
        #pragma unroll
        for (int nt = 0; nt < 4; ++nt) {
            a2[nt] = (f32x4){bb2[nt], bb2[nt], bb2[nt], bb2[nt]};
            short8 w0 = *(const short8*)(W2 + ((0 * 4 + nt) * 64 + lane) * 8);
            short8 w1f = *(const short8*)(W2 + ((1 * 4 + nt) * 64 + lane) * 8);
            a2[nt] = MFMA(A2[0].v, w0, a2[nt]);
            a2[nt] = MFMA(A2[1].v, w1f, a2[nt]);
        }

        ZTRANS(Zw, a2)
        FU A3[2];
        A3[0].v = *(const short8*)(Zw + m16 * 72 + 0 * 32 + q * 8);
        A3[1].v = *(const short8*)(Zw + m16 * 72 + 1 * 32 + q * 8);

        f32x4 a3[4];
        #pragma unroll
        for (int nt = 0; nt < 4; ++nt) {
            a3[nt] = (f32x4){bb3[nt], bb3[nt], bb3[nt], bb3[nt]};
            short8 w0 = *(const short8*)(W3 + ((0 * 4 + nt) * 64 + lane) * 8);
            short8 w1f = *(const short8*)(W3 + ((1 * 4 + nt) * 64 + lane) * 8);
            a3[nt] = MFMA(A3[0].v, w0, a3[nt]);
            a3[nt] = MFMA(A3[1].v, w1f, a3[nt]);
        }

        #pragma unroll
        for (int nt = 0; nt < 4; ++nt)
            #pragma unroll
            for (int r = 0; r < 4; ++r)
                out[(size_t)(n0 + (q << 2) + r) * 64 + nt * 16 + m16] = a3[nt][r];
    }
}

extern "C" void kernel_launch(void* const* d_in, const int* in_sizes, int n_in,
                              void* d_out, int out_size, void* d_ws, size_t ws_size,
                              hipStream_t stream) {
    const float* pos_state  = (const float*)d_in[0];
    const float* pos_action = (const float*)d_in[1];
    const float* h          = (const float*)d_in[2];
    const float* x          = (const float*)d_in[3];
    const float* u          = (const float*)d_in[4];
    const int*   a2s_src    = (const int*)d_in[5];
    const int*   a2s_dst    = (const int*)d_in[6];
    const float* a2s_dis    = (const float*)d_in[7];
    const int*   s2s_src    = (const int*)d_in[8];
    const int*   s2s_dst    = (const int*)d_in[9];
    const float* s2s_dis    = (const float*)d_in[10];
    const float* u2h_w1 = (const float*)d_in[11]; const float* u2h_b1 = (const float*)d_in[12];
    const float* u2h_w2 = (const float*)d_in[13]; const float* u2h_b2 = (const float*)d_in[14];
    const float* u2h_w3 = (const float*)d_in[15]; const float* u2h_b3 = (const float*)d_in[16];
    const float* x2h_w1 = (const float*)d_in[17]; const float* x2h_b1 = (const float*)d_in[18];
    const float* x2h_w2 = (const float*)d_in[19]; const float* x2h_b2 = (const float*)d_in[20];
    const float* x2h_w3 = (const float*)d_in[21]; const float* x2h_b3 = (const float*)d_in[22];
    const float* upd_w1 = (const float*)d_in[23]; const float* upd_b1 = (const float*)d_in[24];
    const float* upd_w2 = (const float*)d_in[25]; const float* upd_b2 = (const float*)d_in[26];
    const float* upd_w3 = (const float*)d_in[27]; const float* upd_b3 = (const float*)d_in[28];

    int NS = in_sizes[0] / 2;
    int NA = in_sizes[1] / 2;
    int EA = in_sizes[5];
    int ES = in_sizes[8];
    int N2 = 2 * NS;
    int NB = (N2 + SCAN_CHUNK - 1) / SCAN_CHUNK;

    char* p = (char*)d_ws;
    int*   cnt2  = (int*)p;            p += (size_t)N2 * 4;       // cnt_s | cnt_a
    size_t zbytes = (size_t)(p - (char*)d_ws);                    // memset: cnt2 only
    float* sum_u = (float*)p;          p += (size_t)NS * 64 * 4;  // zeroed in scatter
    float* sum_x = (float*)p;          p += (size_t)NS * 64 * 4;
    int*   off2   = (int*)p;           p += (size_t)N2 * 4;
    int*   rank_s = (int*)p;           p += (size_t)ES * 4;
    int*   rank_a = (int*)p;           p += (size_t)EA * 4;
    uint2* sd_s   = (uint2*)p;         p += (size_t)ES * 8;       // {src,dis}
    int*   sdst_s = (int*)p;           p += (size_t)ES * 4;
    uint2* sd_a   = (uint2*)p;         p += (size_t)EA * 8;
    int*   sdst_a = (int*)p;           p += (size_t)EA * 4;
    unsigned short* s_row  = (unsigned short*)p; p += (size_t)NS * 80 * 2;
    unsigned short* a_row  = (unsigned short*)p; p += (size_t)NA * 16 * 2;
    int*   bsum   = (int*)p;           p += 128 * 4;
    unsigned short* wtab_s = (unsigned short*)p; p += 7 * 2048 * 2;
    unsigned short* wtab_a = (unsigned short*)p; p += 5 * 2048 * 2;
    unsigned short* wtab_u = (unsigned short*)p; p += 11 * 2048 * 2;
    (void)ws_size;

    int* cnt_s = cnt2;
    int* cnt_a = cnt2 + NS;
    int* off_s = off2;
    int* off_a = off2 + NS;

    hipMemsetAsync(d_ws, 0, zbytes, stream);

    const int MAINB = 2048;
    prep1<<<MAINB + 24, 256, 0, stream>>>(pos_state, pos_action, h, x, u,
                                          s2s_dst, a2s_dst, s_row, a_row,
                                          cnt_s, rank_s, cnt_a, rank_a,
                                          x2h_w1, x2h_w2, x2h_w3,
                                          u2h_w1, u2h_w2, u2h_w3,
                                          upd_w1, upd_w2, upd_w3,
                                          wtab_s, wtab_a, wtab_u,
                                          NS, NA, ES, EA, MAINB);
    scan_a<<<NB, 256, 0, stream>>>(cnt2, bsum, N2);
    scan_b<<<1, 128, 0, stream>>>(bsum, NB);
    scan_c<<<NB, 256, 0, stream>>>(cnt2, bsum, off2, N2, NS, ES);
    scatter_sort2<<<1024, 256, 0, stream>>>(s2s_src, s2s_dst, rank_s, off_s, s2s_dis,
                                            a2s_src, a2s_dst, rank_a, off_a, a2s_dis,
                                            sd_s, sdst_s, sd_a, sdst_a,
                                            sum_u, ES, EA, NS * 32);
    edges_mfma<<<1536, 256, 0, stream>>>(s_row, a_row,
                                         sd_s, sdst_s, sd_a, sdst_a,
                                         wtab_s, wtab_a,
                                         x2h_b1, x2h_b2, x2h_b3,
                                         u2h_b1, u2h_b2, u2h_b3,
                                         pos_state, sum_x, sum_u,
                                         ES, EA, 1120);
    upd_mfma<<<784, 256, 0, stream>>>(pos_state, h, x, sum_u, sum_x, cnt_s,
                                      wtab_u, upd_b1, upd_b2, upd_b3,
                                      (float*)d_out, NS);
}